// Round 2
// baseline (206.122 us; speedup 1.0000x reference)
//
#include <hip/hip_runtime.h>

// ---------------------------------------------------------------------------
// Compile-time Cayley tables for PGA G(3,0,1), basis ordered by grade:
// idx: 0:1 1:e0 2:e1 3:e2 4:e3 5:e01 6:e02 7:e03 8:e12 9:e13 10:e23
//      11:e012 12:e013 13:e023 14:e123 15:e0123
// Blade as 4-bit mask: e0=bit0, e1=bit1, e2=bit2, e3=bit3.
// ---------------------------------------------------------------------------
namespace ga {

constexpr int MASK[16]        = {0,1,2,4,8,3,5,9,6,10,12,7,11,13,14,15};
constexpr int IDX_OF_MASK[16] = {0,1,2,5,3,6,8,11,4,7,9,12,10,13,14,15};

constexpr int popc(int v) { int c = 0; while (v) { c += v & 1; v >>= 1; } return c; }

constexpr int reorder_sign(int a, int b) {
    int s = 0; int t = a >> 1;
    while (t) { s += popc(t & b); t >>= 1; }
    return (s & 1) ? -1 : 1;
}

struct Term { signed char i, j, k, s; };

// Geometric product, metric (0,1,1,1): 192 nonzero terms.
struct GPTab { Term t[192]; };
constexpr GPTab build_gp() {
    GPTab T{}; int n = 0;
    for (int i = 0; i < 16; i++)
        for (int j = 0; j < 16; j++) {
            int a = MASK[i], b = MASK[j];
            if (a & b & 1) continue;                 // e0^2 = 0
            T.t[n].i = (signed char)i;
            T.t[n].j = (signed char)j;
            T.t[n].k = (signed char)IDX_OF_MASK[a ^ b];
            T.t[n].s = (signed char)reorder_sign(a, b);
            n++;
        }
    return T;
}

// Join (sans ref scale): dual(dual(x) ^ dual(y)) folded to 81 terms.
struct JNTab { Term t[81]; };
constexpr JNTab build_join() {
    JNTab T{}; int n = 0;
    int didx[16] = {}, dsgn[16] = {};
    for (int i = 0; i < 16; i++) {
        int a = MASK[i], c = (~a) & 0xF;
        didx[i] = IDX_OF_MASK[c];
        dsgn[i] = reorder_sign(a, c);
    }
    for (int i = 0; i < 16; i++)
        for (int j = 0; j < 16; j++) {
            int p = didx[i], q = didx[j];
            int a = MASK[p], b = MASK[q];
            if (a & b) continue;
            int m = IDX_OF_MASK[a | b];
            int k = didx[m];
            int s = dsgn[i] * dsgn[j] * dsgn[m] * reorder_sign(a, b);
            T.t[n].i = (signed char)i;
            T.t[n].j = (signed char)j;
            T.t[n].k = (signed char)k;
            T.t[n].s = (signed char)s;
            n++;
        }
    return T;
}

constexpr GPTab G = build_gp();
constexpr JNTab J = build_join();

} // namespace ga

// ---------------------------------------------------------------------------
// R9: pure-VGPR dataflow — zero LDS, zero fences, zero DMA.
//
// R8 post-mortem: doubling occupancy (2->4 waves/SIMD) moved dur only 5%
// (49->46.5 us); warm (L3-resident) dispatches == cold -> not read-BW-bound;
// VALUBusy 12%, LDS/L2 traffic ~10x under ceilings -> no shared resource is
// saturated. The remaining cost is the per-wave serial LDS pipeline itself:
// DMA issue -> vmcnt(0) full stall -> conflicted frag reads -> compute ->
// overlay writes -> overlay reads -> stores, with LDS capping residency.
//
// R9 theory: the LDS machinery solves a coalescing problem that doesn't
// exist. Per-lane point-major reads (lane L: 16 B at 64 B stride) are
// L1-coalesced: load k=0 pulls the wave's 4 KB span into L1, k=1..3 hit L1;
// L2/HBM traffic identical to the DMA path. Output is one full 128 B line
// per point, written entirely by its lane (8x dwordx4) -> L2 write-combines,
// no RMW. So: load x,y,ref straight to VGPRs, compute, store straight out.
//   * Accumulator split: compute gp[16] -> store -> reuse regs for jn[16]
//     -> store. Live set ~60 VGPRs (xx16+yy16+acc16+addr).
//   * __launch_bounds__(256, 6): cap ~84 VGPR (no spill risk for ~60 live),
//     6 waves/SIMD = 24 waves/CU, 2.5x R8 residency. 256-thread blocks
//     avoid any 16-workgroup/CU cap that 1-wave blocks can hit.
//   * No separate tail kernel: per-thread bounds guard covers any npts.
// ---------------------------------------------------------------------------

__global__ __launch_bounds__(256, 6)
void MVGeometricBilinear_kernel(const float* __restrict__ x,
                                const float* __restrict__ y,
                                const float* __restrict__ ref,
                                float* __restrict__ out,
                                int npts)
{
    const int pt = blockIdx.x * 256 + threadIdx.x;
    if (pt >= npts) return;

    // ---- per-lane loads: 4x dwordx4 each for x,y; 1 dword for ref_e0123 ----
    const float4* xp = reinterpret_cast<const float4*>(x) + (size_t)pt * 4;
    const float4* yp = reinterpret_cast<const float4*>(y) + (size_t)pt * 4;
    float xx[16], yy[16];
#pragma unroll
    for (int k = 0; k < 4; k++) {
        const float4 vx = xp[k];
        const float4 vy = yp[k];
        xx[4*k+0] = vx.x; xx[4*k+1] = vx.y; xx[4*k+2] = vx.z; xx[4*k+3] = vx.w;
        yy[4*k+0] = vy.x; yy[4*k+1] = vy.y; yy[4*k+2] = vy.z; yy[4*k+3] = vy.w;
    }
    const float r = ref[(size_t)pt * 16 + 15];

    float4* op = reinterpret_cast<float4*>(out) + (size_t)pt * 8;

    // ---- phase 1: geometric product (192 terms), store first half-line ----
    {
        float gp[16] = {0.f, 0.f, 0.f, 0.f, 0.f, 0.f, 0.f, 0.f,
                        0.f, 0.f, 0.f, 0.f, 0.f, 0.f, 0.f, 0.f};
#pragma unroll
        for (int t = 0; t < 192; t++) {
            const int ti = ga::G.t[t].i, tj = ga::G.t[t].j, tk = ga::G.t[t].k;
            const float v = xx[ti] * yy[tj];
            if (ga::G.t[t].s > 0) gp[tk] += v; else gp[tk] -= v;
        }
#pragma unroll
        for (int k = 0; k < 4; k++)
            op[k] = make_float4(gp[4*k+0], gp[4*k+1], gp[4*k+2], gp[4*k+3]);
    }

    // ---- phase 2: join (81 terms), scale by ref_e0123, second half-line ----
    {
        float jn[16] = {0.f, 0.f, 0.f, 0.f, 0.f, 0.f, 0.f, 0.f,
                        0.f, 0.f, 0.f, 0.f, 0.f, 0.f, 0.f, 0.f};
#pragma unroll
        for (int t = 0; t < 81; t++) {
            const int ti = ga::J.t[t].i, tj = ga::J.t[t].j, tk = ga::J.t[t].k;
            const float v = xx[ti] * yy[tj];
            if (ga::J.t[t].s > 0) jn[tk] += v; else jn[tk] -= v;
        }
#pragma unroll
        for (int k = 0; k < 4; k++)
            op[4 + k] = make_float4(r * jn[4*k+0], r * jn[4*k+1],
                                    r * jn[4*k+2], r * jn[4*k+3]);
    }
}

extern "C" void kernel_launch(void* const* d_in, const int* in_sizes, int n_in,
                              void* d_out, int out_size, void* d_ws, size_t ws_size,
                              hipStream_t stream) {
    const float* x   = (const float*)d_in[0];
    const float* y   = (const float*)d_in[1];
    const float* ref = (const float*)d_in[2];
    float* out = (float*)d_out;

    const int npts   = in_sizes[0] / 16;          // B*T = 524288
    const int blocks = (npts + 255) / 256;        // 2048

    if (npts > 0) {
        MVGeometricBilinear_kernel<<<blocks, 256, 0, stream>>>(
            x, y, ref, out, npts);
    }
}

// Round 3
// 160.700 us; speedup vs baseline: 1.2827x; 1.2827x over previous
//
#include <hip/hip_runtime.h>

// ---------------------------------------------------------------------------
// Compile-time Cayley tables for PGA G(3,0,1), basis ordered by grade:
// idx: 0:1 1:e0 2:e1 3:e2 4:e3 5:e01 6:e02 7:e03 8:e12 9:e13 10:e23
//      11:e012 12:e013 13:e023 14:e123 15:e0123
// Blade as 4-bit mask: e0=bit0, e1=bit1, e2=bit2, e3=bit3.
// ---------------------------------------------------------------------------
namespace ga {

constexpr int MASK[16]        = {0,1,2,4,8,3,5,9,6,10,12,7,11,13,14,15};
constexpr int IDX_OF_MASK[16] = {0,1,2,5,3,6,8,11,4,7,9,12,10,13,14,15};

constexpr int popc(int v) { int c = 0; while (v) { c += v & 1; v >>= 1; } return c; }

constexpr int reorder_sign(int a, int b) {
    int s = 0; int t = a >> 1;
    while (t) { s += popc(t & b); t >>= 1; }
    return (s & 1) ? -1 : 1;
}

struct Term { signed char i, j, k, s; };

// Geometric product, metric (0,1,1,1): 192 nonzero terms.
struct GPTab { Term t[192]; };
constexpr GPTab build_gp() {
    GPTab T{}; int n = 0;
    for (int i = 0; i < 16; i++)
        for (int j = 0; j < 16; j++) {
            int a = MASK[i], b = MASK[j];
            if (a & b & 1) continue;                 // e0^2 = 0
            T.t[n].i = (signed char)i;
            T.t[n].j = (signed char)j;
            T.t[n].k = (signed char)IDX_OF_MASK[a ^ b];
            T.t[n].s = (signed char)reorder_sign(a, b);
            n++;
        }
    return T;
}

// Join (sans ref scale): dual(dual(x) ^ dual(y)) folded to 81 terms.
struct JNTab { Term t[81]; };
constexpr JNTab build_join() {
    JNTab T{}; int n = 0;
    int didx[16] = {}, dsgn[16] = {};
    for (int i = 0; i < 16; i++) {
        int a = MASK[i], c = (~a) & 0xF;
        didx[i] = IDX_OF_MASK[c];
        dsgn[i] = reorder_sign(a, c);
    }
    for (int i = 0; i < 16; i++)
        for (int j = 0; j < 16; j++) {
            int p = didx[i], q = didx[j];
            int a = MASK[p], b = MASK[q];
            if (a & b) continue;
            int m = IDX_OF_MASK[a | b];
            int k = didx[m];
            int s = dsgn[i] * dsgn[j] * dsgn[m] * reorder_sign(a, b);
            T.t[n].i = (signed char)i;
            T.t[n].j = (signed char)j;
            T.t[n].k = (signed char)k;
            T.t[n].s = (signed char)s;
            n++;
        }
    return T;
}

constexpr GPTab G = build_gp();
constexpr JNTab J = build_join();

} // namespace ga

// ---------------------------------------------------------------------------
// R10: pure-VGPR dataflow, spill-free.
//
// R9 post-mortem: __launch_bounds__(256, 6) forced VGPR_Count down to 40 for
// a ~60-register live set -> scratch spills. Evidence: WRITE_SIZE 65->189 MB
// (spill-store evictions; spill reads were L2-hits so FETCH stayed at the
// 96 MB input footprint), VALUBusy 5.4%, dur 106 us. The pure-VGPR idea was
// never actually measured — it ran as a scratch-memory kernel.
// What R9 DID confirm: per-lane strided reads fetch exactly the input bytes
// (FETCH 95.8 MB) and per-lane line-owned stores need no LDS transpose
// (bank conflicts 0).
//
// R10: identical structure, __launch_bounds__(256, 4) -> VGPR cap 128.
// Live set ~60 fits with slack -> no spills; compiler lands ~64-96 VGPRs ->
// 4-8 waves/SIMD (LDS=0, nothing else caps). Per-wave critical path:
// issue 9 loads -> one wait -> ~550 cy compute -> 8 fire-and-forget stores.
//
//   * 32-bit offsets everywhere (arrays < 256 MB): SGPR base + voffset
//     addressing, minimal address VGPRs.
//   * Accumulator phases (gp then jn) to keep peak pressure down.
//   * Per-thread bounds guard covers any npts; no tail kernel.
// ---------------------------------------------------------------------------

__global__ __launch_bounds__(256, 4)
void MVGeometricBilinear_kernel(const float* __restrict__ x,
                                const float* __restrict__ y,
                                const float* __restrict__ ref,
                                float* __restrict__ out,
                                int npts)
{
    const unsigned pt = blockIdx.x * 256u + threadIdx.x;
    if (pt >= (unsigned)npts) return;

    // ---- per-lane loads: 4x dwordx4 each for x,y; 1 dword for ref_e0123 ----
    const float4* xp = reinterpret_cast<const float4*>(x) + pt * 4u;
    const float4* yp = reinterpret_cast<const float4*>(y) + pt * 4u;
    float xx[16], yy[16];
#pragma unroll
    for (int k = 0; k < 4; k++) {
        const float4 vx = xp[k];
        const float4 vy = yp[k];
        xx[4*k+0] = vx.x; xx[4*k+1] = vx.y; xx[4*k+2] = vx.z; xx[4*k+3] = vx.w;
        yy[4*k+0] = vy.x; yy[4*k+1] = vy.y; yy[4*k+2] = vy.z; yy[4*k+3] = vy.w;
    }
    const float r = ref[pt * 16u + 15u];

    float4* op = reinterpret_cast<float4*>(out) + pt * 8u;

    // ---- phase 1: geometric product (192 terms), store first half-line ----
    {
        float gp[16] = {0.f, 0.f, 0.f, 0.f, 0.f, 0.f, 0.f, 0.f,
                        0.f, 0.f, 0.f, 0.f, 0.f, 0.f, 0.f, 0.f};
#pragma unroll
        for (int t = 0; t < 192; t++) {
            const int ti = ga::G.t[t].i, tj = ga::G.t[t].j, tk = ga::G.t[t].k;
            const float v = xx[ti] * yy[tj];
            if (ga::G.t[t].s > 0) gp[tk] += v; else gp[tk] -= v;
        }
#pragma unroll
        for (int k = 0; k < 4; k++)
            op[k] = make_float4(gp[4*k+0], gp[4*k+1], gp[4*k+2], gp[4*k+3]);
    }

    // ---- phase 2: join (81 terms), scale by ref_e0123, second half-line ----
    {
        float jn[16] = {0.f, 0.f, 0.f, 0.f, 0.f, 0.f, 0.f, 0.f,
                        0.f, 0.f, 0.f, 0.f, 0.f, 0.f, 0.f, 0.f};
#pragma unroll
        for (int t = 0; t < 81; t++) {
            const int ti = ga::J.t[t].i, tj = ga::J.t[t].j, tk = ga::J.t[t].k;
            const float v = xx[ti] * yy[tj];
            if (ga::J.t[t].s > 0) jn[tk] += v; else jn[tk] -= v;
        }
#pragma unroll
        for (int k = 0; k < 4; k++)
            op[4 + k] = make_float4(r * jn[4*k+0], r * jn[4*k+1],
                                    r * jn[4*k+2], r * jn[4*k+3]);
    }
}

extern "C" void kernel_launch(void* const* d_in, const int* in_sizes, int n_in,
                              void* d_out, int out_size, void* d_ws, size_t ws_size,
                              hipStream_t stream) {
    const float* x   = (const float*)d_in[0];
    const float* y   = (const float*)d_in[1];
    const float* ref = (const float*)d_in[2];
    float* out = (float*)d_out;

    const int npts   = in_sizes[0] / 16;          // B*T = 524288
    const int blocks = (npts + 255) / 256;        // 2048

    if (npts > 0) {
        MVGeometricBilinear_kernel<<<blocks, 256, 0, stream>>>(
            x, y, ref, out, npts);
    }
}

// Round 4
// 147.645 us; speedup vs baseline: 1.3961x; 1.0884x over previous
//
#include <hip/hip_runtime.h>

// ---------------------------------------------------------------------------
// Compile-time Cayley tables for PGA G(3,0,1), basis ordered by grade:
// idx: 0:1 1:e0 2:e1 3:e2 4:e3 5:e01 6:e02 7:e03 8:e12 9:e13 10:e23
//      11:e012 12:e013 13:e023 14:e123 15:e0123
// Blade as 4-bit mask: e0=bit0, e1=bit1, e2=bit2, e3=bit3.
// ---------------------------------------------------------------------------
namespace ga {

constexpr int MASK[16]        = {0,1,2,4,8,3,5,9,6,10,12,7,11,13,14,15};
constexpr int IDX_OF_MASK[16] = {0,1,2,5,3,6,8,11,4,7,9,12,10,13,14,15};

constexpr int popc(int v) { int c = 0; while (v) { c += v & 1; v >>= 1; } return c; }

constexpr int reorder_sign(int a, int b) {
    int s = 0; int t = a >> 1;
    while (t) { s += popc(t & b); t >>= 1; }
    return (s & 1) ? -1 : 1;
}

struct Term { signed char i, j, k, s; };

// Geometric product, metric (0,1,1,1): 192 nonzero terms.
// By output blade: e0-containing outputs have 16 terms, others 8 ->
// outputs k<8 carry exactly 96 terms, k>=8 exactly 96 (perfect 2-way split).
struct GPTab { Term t[192]; };
constexpr GPTab build_gp() {
    GPTab T{}; int n = 0;
    for (int i = 0; i < 16; i++)
        for (int j = 0; j < 16; j++) {
            int a = MASK[i], b = MASK[j];
            if (a & b & 1) continue;                 // e0^2 = 0
            T.t[n].i = (signed char)i;
            T.t[n].j = (signed char)j;
            T.t[n].k = (signed char)IDX_OF_MASK[a ^ b];
            T.t[n].s = (signed char)reorder_sign(a, b);
            n++;
        }
    return T;
}

// Join (sans ref scale): dual(dual(x) ^ dual(y)) folded to 81 terms.
struct JNTab { Term t[81]; };
constexpr JNTab build_join() {
    JNTab T{}; int n = 0;
    int didx[16] = {}, dsgn[16] = {};
    for (int i = 0; i < 16; i++) {
        int a = MASK[i], c = (~a) & 0xF;
        didx[i] = IDX_OF_MASK[c];
        dsgn[i] = reorder_sign(a, c);
    }
    for (int i = 0; i < 16; i++)
        for (int j = 0; j < 16; j++) {
            int p = didx[i], q = didx[j];
            int a = MASK[p], b = MASK[q];
            if (a & b) continue;
            int m = IDX_OF_MASK[a | b];
            int k = didx[m];
            int s = dsgn[i] * dsgn[j] * dsgn[m] * reorder_sign(a, b);
            T.t[n].i = (signed char)i;
            T.t[n].j = (signed char)j;
            T.t[n].k = (signed char)k;
            T.t[n].s = (signed char)s;
            n++;
        }
    return T;
}

constexpr GPTab G = build_gp();
constexpr JNTab J = build_join();

} // namespace ga

// ---------------------------------------------------------------------------
// R11: 2-wave blocks, output-split compute, 20 waves/CU, counted-vmcnt
// pipeline, all-conflict-free LDS.
//
// Ladder so far: R7 (8 w/CU + pipeline) 49us; R8 (16 w/CU, no pipe) 46.5;
// R10 (uncoalesced, ~10 w/CU) 64. Nothing shared saturates (warm==cold,
// VALUBusy<=12%, LDS/L2 >=10x under ceilings) -> dur scales with per-wave
// serial path / resident waves. R10 also showed uncoalesced stores inflate
// WRITE_SIZE 1.45x. So: keep everything coalesced, halve the per-wave path,
// double residency, and pipeline.
//
//   * Block = 128 thr (2 waves) on one 64-pt chunk. Wave w computes output
//     indices k in [8w, 8w+8) of BOTH gp and jn for its lane's point:
//     gp splits 96/96 exactly; jn ~40/41. ~145 terms/wave vs 289.
//   * LDS = 2 x 2048 floats (x|y double-buffer) = 16384 B exactly
//     -> 10 blocks/CU = 20 waves/CU. ref is per-lane VGPR (prologue).
//   * DMA (global_load_lds, 16B) with PRE-SWIZZLED per-lane source
//     addresses so point-major frag reads are bank-conflict-free:
//     LDS float4-slot s of point p holds global group j=(s-t)&3, t=(p>>1)&3.
//   * Output overlay over the consumed buffer, stride 32 + XOR swizzle
//     (q^(p&7)): fits in exactly 2048 floats, conflict-free writes and
//     gathers, single phase. Cooperative stores: 4 x dwordx4/lane, lane-
//     consecutive -> 1KB/instruction.
//   * Counted vmcnt: steady-state vmcnt(8) = keep [stores i-1 (4), DMA i+1
//     (4)] in flight; never drain to 0 mid-loop. Raw s_barrier + explicit
//     lgkmcnt(0) only (NO __syncthreads — it emits vmcnt(0) and would
//     drain the pipeline).
// ---------------------------------------------------------------------------

typedef const __attribute__((address_space(1))) void* gas_ptr;
typedef __attribute__((address_space(3))) void*       las_ptr;

constexpr int NITER = 4;

template<int HALF>
__device__ __forceinline__ void accum_half(const float* __restrict__ xx,
                                           const float* __restrict__ yy,
                                           float* __restrict__ acc,   // gp[8*HALF .. +8)
                                           float* __restrict__ jacc)  // jn[8*HALF .. +8)
{
#pragma unroll
    for (int t = 0; t < 192; t++) {
        const int tk = ga::G.t[t].k;
        if ((tk < 8) != (HALF == 0)) continue;       // folds: t is unroll-const
        const float v = xx[ga::G.t[t].i] * yy[ga::G.t[t].j];
        if (ga::G.t[t].s > 0) acc[tk & 7] += v; else acc[tk & 7] -= v;
    }
#pragma unroll
    for (int t = 0; t < 81; t++) {
        const int tk = ga::J.t[t].k;
        if ((tk < 8) != (HALF == 0)) continue;
        const float v = xx[ga::J.t[t].i] * yy[ga::J.t[t].j];
        if (ga::J.t[t].s > 0) jacc[tk & 7] += v; else jacc[tk & 7] -= v;
    }
}

__global__ __launch_bounds__(128, 4)
void MVGeometricBilinear_kernel(const float* __restrict__ x,
                                const float* __restrict__ y,
                                const float* __restrict__ ref,
                                float* __restrict__ out,
                                int nchunks, int gstride)
{
    __shared__ __align__(16) float buf[2][2048];

    const int tid  = threadIdx.x;
    const int lane = tid & 63;
    const int wid  = tid >> 6;                 // 0: x-loader/gp-lo half, 1: y/hi

    const long chunk0 = blockIdx.x;
    if (chunk0 >= nchunks) return;

    // ---- per-lane ref prologue (rr[it] in regs; drained by first vmcnt) ----
    float rr[NITER];
    {
        long c = chunk0;
#pragma unroll
        for (int it = 0; it < NITER; ++it) {
            if (c < nchunks) rr[it] = ref[(c * 64 + lane) * 16 + 15];
            c += gstride;
        }
    }

    // ---- precomputed swizzle offsets ----
    // DMA op k lands lane L at LDS float4-slot (k*64 + L) [HW rule].
    // Slot s-group within point p stores global group j = (s - t)&3, t=(p>>1)&3
    // -> per-lane swizzled global source; frag read for group j at slot-group
    // (j + t)&3. Bank-conflict-free b128 frag reads (verified: 8-lane groups
    // cover 8 distinct 16B slots mod 32 banks).
    int srcoff[4];   // global float4 offset within chunk for my DMA op k
    int fragoff[4];  // LDS word addr of my point's group k (x region; y = +1024)
#pragma unroll
    for (int k = 0; k < 4; ++k) {
        const int slot = k * 64 + lane;
        const int j = ((slot & 3) - ((slot >> 3) & 3)) & 3;
        srcoff[k] = (slot & ~3) | j;
        const int s = (k + ((lane >> 1) & 3)) & 3;
        fragoff[k] = lane * 16 + (s << 2);
    }

    const float4* gsrc = reinterpret_cast<const float4*>(wid ? y : x);
    const int ldsbase = wid ? 1024 : 0;        // words; wave-uniform dst base

    auto dma = [&](long c, int b) {
#pragma unroll
        for (int k = 0; k < 4; ++k)
            __builtin_amdgcn_global_load_lds(
                (gas_ptr)(gsrc + c * 256 + srcoff[k]),
                (las_ptr)(&buf[b][ldsbase + k * 256]), 16, 0, 0);
    };

    long chunk = chunk0;
    int cur = 0;
    dma(chunk, 0);                             // prologue: chunk0 -> buffer A

#pragma unroll
    for (int it = 0; it < NITER; ++it) {
        const long next = chunk + gstride;
        const bool pf = (it + 1 < NITER) && (next < nchunks);
        if (pf) dma(next, cur ^ 1);

        // Drain my DMA for chunk `it` (oldest); keep [stores it-1, DMA it+1].
        if (it == 0) {
            if (pf) asm volatile("s_waitcnt vmcnt(4)" ::: "memory");
            else    asm volatile("s_waitcnt vmcnt(0)" ::: "memory");
        } else {
            if (pf) asm volatile("s_waitcnt vmcnt(8)" ::: "memory");
            else    asm volatile("s_waitcnt vmcnt(4)" ::: "memory");
        }
        __builtin_amdgcn_s_barrier();          // B1: both waves' halves landed

        // ---- fragments: 8 x ds_read_b128, swizzle-conflict-free ----
        float xx[16], yy[16];
#pragma unroll
        for (int k = 0; k < 4; ++k) {
            const float4 vx = *reinterpret_cast<const float4*>(&buf[cur][fragoff[k]]);
            const float4 vy = *reinterpret_cast<const float4*>(&buf[cur][1024 + fragoff[k]]);
            xx[4*k+0] = vx.x; xx[4*k+1] = vx.y; xx[4*k+2] = vx.z; xx[4*k+3] = vx.w;
            yy[4*k+0] = vy.x; yy[4*k+1] = vy.y; yy[4*k+2] = vy.z; yy[4*k+3] = vy.w;
        }
        asm volatile("s_waitcnt lgkmcnt(0)" ::: "memory");
        __builtin_amdgcn_s_barrier();          // B2: frags done -> buf[cur] free

        // ---- compute my output half (~145 terms) ----
        float acc[8]  = {0.f,0.f,0.f,0.f,0.f,0.f,0.f,0.f};
        float jacc[8] = {0.f,0.f,0.f,0.f,0.f,0.f,0.f,0.f};
        if (wid == 0) accum_half<0>(xx, yy, acc, jacc);
        else          accum_half<1>(xx, yy, acc, jacc);
        const float r = rr[it];

        // ---- overlay: stride 32 + XOR(q^(p&7)) swizzle over buf[cur] ----
        // quarters: wave0 -> q {0,1} gp[0..7], {4,5} r*jn[0..7];
        //           wave1 -> q {2,3} gp[8..15], {6,7} r*jn[8..15].
        {
            float* lo = &buf[cur][0];
            const int pb = lane * 32, px = lane & 7;
            const int qg = 2 * wid, qj = 4 + 2 * wid;
            *reinterpret_cast<float4*>(lo + pb + (((qg    ) ^ px) << 2)) =
                make_float4(acc[0], acc[1], acc[2], acc[3]);
            *reinterpret_cast<float4*>(lo + pb + (((qg + 1) ^ px) << 2)) =
                make_float4(acc[4], acc[5], acc[6], acc[7]);
            *reinterpret_cast<float4*>(lo + pb + (((qj    ) ^ px) << 2)) =
                make_float4(r*jacc[0], r*jacc[1], r*jacc[2], r*jacc[3]);
            *reinterpret_cast<float4*>(lo + pb + (((qj + 1) ^ px) << 2)) =
                make_float4(r*jacc[4], r*jacc[5], r*jacc[6], r*jacc[7]);
        }
        asm volatile("s_waitcnt lgkmcnt(0)" ::: "memory");
        __builtin_amdgcn_s_barrier();          // B3: overlay complete

        // ---- cooperative coalesced store: 4 x dwordx4 per lane ----
        {
            float4* go = reinterpret_cast<float4*>(out) + chunk * 512;
#pragma unroll
            for (int c = 0; c < 4; ++c) {
                const int g = c * 128 + wid * 64 + lane;   // lane-consecutive
                const int p = g >> 3, q = g & 7;
                go[g] = *reinterpret_cast<const float4*>(
                            &buf[cur][p * 32 + ((q ^ (p & 7)) << 2)]);
            }
        }
        asm volatile("s_waitcnt lgkmcnt(0)" ::: "memory");
        __builtin_amdgcn_s_barrier();          // B4: gathers done -> next DMA
                                               //     into buf[cur] is safe

        if (!pf) break;
        cur ^= 1;
        chunk = next;
    }
}

// Tail path (npts not divisible by 64) — scalar per-thread, same math.
__global__ __launch_bounds__(64)
void MVGeometricBilinear_tail(const float* __restrict__ x,
                              const float* __restrict__ y,
                              const float* __restrict__ ref,
                              float* __restrict__ out,
                              int start, int npts)
{
    int pt = start + blockIdx.x * 64 + threadIdx.x;
    if (pt >= npts) return;
    float xx[16], yy[16];
#pragma unroll
    for (int k = 0; k < 16; k++) { xx[k] = x[(size_t)pt*16+k]; yy[k] = y[(size_t)pt*16+k]; }
    const float r = ref[(size_t)pt*16+15];
    float gp[16] = {}, jn[16] = {};
#pragma unroll
    for (int t = 0; t < 192; t++) {
        const float v = xx[ga::G.t[t].i] * yy[ga::G.t[t].j];
        if (ga::G.t[t].s > 0) gp[ga::G.t[t].k] += v; else gp[ga::G.t[t].k] -= v;
    }
#pragma unroll
    for (int t = 0; t < 81; t++) {
        const float v = xx[ga::J.t[t].i] * yy[ga::J.t[t].j];
        if (ga::J.t[t].s > 0) jn[ga::J.t[t].k] += v; else jn[ga::J.t[t].k] -= v;
    }
#pragma unroll
    for (int k = 0; k < 16; k++) out[(size_t)pt*32+k] = gp[k];
#pragma unroll
    for (int k = 0; k < 16; k++) out[(size_t)pt*32+16+k] = r * jn[k];
}

extern "C" void kernel_launch(void* const* d_in, const int* in_sizes, int n_in,
                              void* d_out, int out_size, void* d_ws, size_t ws_size,
                              hipStream_t stream) {
    const float* x   = (const float*)d_in[0];
    const float* y   = (const float*)d_in[1];
    const float* ref = (const float*)d_in[2];
    float* out = (float*)d_out;

    const int npts    = in_sizes[0] / 16;     // B*T = 524288
    const int nchunks = npts / 64;            // 8192

    if (nchunks > 0) {
        // 10 blocks/CU x 256 CUs = 2560 persistent-ish blocks; each handles
        // ceil(nchunks/2560) <= NITER chunks via grid stride.
        int blocks = nchunks < 2560 ? nchunks : 2560;
        const int need = (nchunks + NITER - 1) / NITER;
        if (blocks < need) blocks = need;
        MVGeometricBilinear_kernel<<<blocks, 128, 0, stream>>>(
            x, y, ref, out, nchunks, blocks);
    }

    const int rem = npts - nchunks * 64;      // 0 for this shape
    if (rem > 0) {
        MVGeometricBilinear_tail<<<(rem + 63) / 64, 64, 0, stream>>>(
            x, y, ref, out, nchunks * 64, npts);
    }
}